// Round 4
// baseline (178.897 us; speedup 1.0000x reference)
//
#include <hip/hip_runtime.h>

typedef __attribute__((ext_vector_type(8))) short short8;
typedef __attribute__((ext_vector_type(16))) float floatx16;
typedef __attribute__((ext_vector_type(4))) float floatx4;
typedef unsigned short ushort16_t;
typedef unsigned int uint32;

#define BB 8
#define CC 384
#define NPIX 1024
#define TOTCH 176      // 64 q + 16 k + 96 v
#define BN_EPS 1e-5f

// ---------- helpers ----------
__device__ __forceinline__ ushort16_t f2bf(float x) {
    uint32 u = __float_as_uint(x);
    u += 0x7FFFu + ((u >> 16) & 1u);
    return (ushort16_t)(u >> 16);
}
__device__ __forceinline__ uint32 pk2(float a, float b) {
    uint32 ua = __float_as_uint(a); ua += 0x7FFFu + ((ua >> 16) & 1u);
    uint32 ub = __float_as_uint(b); ub += 0x7FFFu + ((ub >> 16) & 1u);
    return (ua >> 16) | (ub & 0xFFFF0000u);
}
__device__ __forceinline__ int div48(int x) {   // valid for x < 16384
    return (int)(((unsigned)x * 21846u) >> 20);
}
// lgkmcnt(0), vmcnt unconstrained (63), expcnt unconstrained (7)
#define LGKM0_ONLY 0xC07F

// ws layout (float units):
// qkv  [B][176][N]        @ 0         (1441792)
// sA   [176]              @ 1441792
// sB   [176]              @ 1441968
// ksm  [B][16][N]         @ 1442144   (131072)
// qt_g bf16 [n][kh2][bh32][8]                 @f 1573216 (262144 f)
// vt_g bf16 [b][mt32][vh2][vt3][mq4][v16][8]  @f 1835360 (393216 f)
// lc_g bf16 [b][vh2][vt3][mq4][v16][8]        @f 2228576 (12288 f)
// wbf  bf16 [row192][c384]                    @f 3813728 (36864 f)

// ---------------- K0: W -> bf16 wbf (tiny) ----------------------------------
// launch_bounds min-waves=2: cap register target at 2 waves/EU so the
// allocator keeps prefetch loads in flight (VGPR 64 -> ~256 budget).
__global__ __launch_bounds__(256, 2) void k_wt(const float* __restrict__ Wq,
    const float* __restrict__ Wk, const float* __restrict__ Wv,
    ushort16_t* __restrict__ wbf)
{
    int bx = blockIdx.x, t = threadIdx.x;
    #pragma unroll
    for (int jj = 0; jj < 9; ++jj) {
        int idx8 = (bx * 9 + jj) * 256 + t;   // [0, 9216)
        int row = div48(idx8);
        int g   = idx8 - row * 48;
        float4 f0, f1;
        if (row < 176) {
            const float* src;
            if (row < 64)       src = Wq + (size_t)row * CC;
            else if (row < 80)  src = Wk + (size_t)(row - 64) * CC;
            else                src = Wv + (size_t)(row - 80) * CC;
            f0 = *(const float4*)(src + g * 8);
            f1 = *(const float4*)(src + g * 8 + 4);
        } else {
            f0.x = f0.y = f0.z = f0.w = 0.f;
            f1 = f0;
        }
        uint4 w;
        w.x = pk2(f0.x, f0.y); w.y = pk2(f0.z, f0.w);
        w.z = pk2(f1.x, f1.y); w.w = pk2(f1.z, f1.w);
        *(uint4*)&wbf[(size_t)row * CC + g * 8] = w;
    }
}

// ---------------- K1: fused transpose + q/k/v projection (MFMA) -------------
__global__ __launch_bounds__(256, 2) void k_proj(const float* __restrict__ x,
    const ushort16_t* __restrict__ wbf, float* __restrict__ qkv)
{
    __shared__ __align__(16) ushort16_t XT[32 * 392];  // 24.5 KB, pad 392
    int bx = blockIdx.x, t = threadIdx.x;
    int b = bx >> 5, nbase = (bx & 31) * 32;
    const float* xb = x + (size_t)b * (CC * NPIX) + nbase;
    #pragma unroll
    for (int j = 0; j < 12; ++j) {
        int idx = t + 256 * j;           // [0, 3072) = 384 c x 8 n-groups
        int c = idx >> 3, ng = idx & 7;
        float4 f = *(const float4*)(xb + (size_t)c * NPIX + ng * 4);
        int col = ng * 4;
        XT[(col + 0) * 392 + c] = f2bf(f.x);
        XT[(col + 1) * 392 + c] = f2bf(f.y);
        XT[(col + 2) * 392 + c] = f2bf(f.z);
        XT[(col + 3) * 392 + c] = f2bf(f.w);
    }
    __syncthreads();

    int wave = t >> 6, lane = t & 63;
    int ct = wave & 1;            // col-tile (16 cols)
    int rs = wave >> 1;           // row-tile parity
    int col1 = lane & 15, kq = lane >> 4;
    const ushort16_t* bbase = &XT[(ct * 16 + col1) * 392 + kq * 8];
    int n = nbase + ct * 16 + col1;

    for (int r = rs; r < 11; r += 2) {
        int r0 = r * 16;
        const ushort16_t* ap = wbf + (size_t)(r0 + col1) * CC + kq * 8;
        floatx4 acc = {0.f, 0.f, 0.f, 0.f};
        short8 a0 = *(const short8*)ap;
        short8 b0 = *(const short8*)bbase;
        #pragma unroll
        for (int k = 1; k < 12; ++k) {
            short8 a1 = *(const short8*)(ap + k * 32);
            short8 b1 = *(const short8*)(bbase + k * 32);
            acc = __builtin_amdgcn_mfma_f32_16x16x32_bf16(a0, b0, acc, 0, 0, 0);
            a0 = a1; b0 = b1;
        }
        acc = __builtin_amdgcn_mfma_f32_16x16x32_bf16(a0, b0, acc, 0, 0, 0);
        #pragma unroll
        for (int rr = 0; rr < 4; ++rr) {
            int ch = r0 + kq * 4 + rr;
            qkv[((size_t)b * TOTCH + ch) * NPIX + n] = acc[rr];
        }
    }
}

// ---------------- K2: BN stats + softmax (merged, float4) -------------------
__global__ __launch_bounds__(256, 2) void k_bnsm(const float* __restrict__ qkv,
    const float* __restrict__ gq, const float* __restrict__ bq,
    const float* __restrict__ gv, const float* __restrict__ bv,
    float* __restrict__ sA, float* __restrict__ sB, float* __restrict__ ksm)
{
    int bx = blockIdx.x, tid = threadIdx.x;
    int wid = tid >> 6, lane = tid & 63;
    if (bx < 160) {
        int ch = bx;
        int row; float gamma, beta;
        if (ch < 64) { row = ch; gamma = gq[ch]; beta = bq[ch]; }
        else { int j = ch - 64; row = 80 + j; gamma = gv[j]; beta = bv[j]; }
        float s = 0.f, ss = 0.f;
        #pragma unroll
        for (int j = 0; j < 8; ++j) {
            int i4 = tid + 256 * j;
            int b = i4 >> 8, n4 = i4 & 255;
            float4 f = *(const float4*)(qkv + ((size_t)b * TOTCH + row) * NPIX
                                            + n4 * 4);
            s  += f.x + f.y + f.z + f.w;
            ss += f.x * f.x + f.y * f.y + f.z * f.z + f.w * f.w;
        }
        #pragma unroll
        for (int off = 32; off > 0; off >>= 1) {
            s  += __shfl_down(s, off);
            ss += __shfl_down(ss, off);
        }
        __shared__ float rs[4], rss[4];
        if (lane == 0) { rs[wid] = s; rss[wid] = ss; }
        __syncthreads();
        if (tid == 0) {
            float S  = rs[0] + rs[1] + rs[2] + rs[3];
            float SS = rss[0] + rss[1] + rss[2] + rss[3];
            float inv = 1.f / (BB * NPIX);
            float mean = S * inv;
            float var  = SS * inv - mean * mean;
            float a = gamma * rsqrtf(var + BN_EPS);
            sA[row] = a;
            sB[row] = beta - mean * a;
        }
    } else {
        int idx = bx - 160;
        int kc = idx & 15, b = idx >> 4;
        const float* rowp = qkv + ((size_t)b * TOTCH + 64 + kc) * NPIX;
        float4 v4 = *(const float4*)(rowp + tid * 4);
        float v[4] = {v4.x, v4.y, v4.z, v4.w};
        float mx = fmaxf(fmaxf(v[0], v[1]), fmaxf(v[2], v[3]));
        #pragma unroll
        for (int off = 32; off > 0; off >>= 1) mx = fmaxf(mx, __shfl_down(mx, off));
        __shared__ float sm[4], ssum[4];
        if (lane == 0) sm[wid] = mx;
        __syncthreads();
        mx = fmaxf(fmaxf(sm[0], sm[1]), fmaxf(sm[2], sm[3]));
        float e[4], s = 0.f;
        #pragma unroll
        for (int j = 0; j < 4; ++j) { e[j] = __expf(v[j] - mx); s += e[j]; }
        #pragma unroll
        for (int off = 32; off > 0; off >>= 1) s += __shfl_down(s, off);
        if (lane == 0) ssum[wid] = s;
        __syncthreads();
        float inv = 1.f / (ssum[0] + ssum[1] + ssum[2] + ssum[3]);
        float4 o;
        o.x = e[0] * inv; o.y = e[1] * inv; o.z = e[2] * inv; o.w = e[3] * inv;
        *(float4*)(ksm + ((size_t)b * 16 + kc) * NPIX + tid * 4) = o;
    }
}

// ---------------- K3: pack q/v (bf16 tiled) + content lambda (fused) --------
__global__ __launch_bounds__(256, 2) void k_packlc(const float* __restrict__ qkv,
    const float* __restrict__ sA, const float* __restrict__ sB,
    const float* __restrict__ ksm,
    ushort16_t* __restrict__ qt_g, ushort16_t* __restrict__ vt_g,
    ushort16_t* __restrict__ lc_g)
{
    int bx = blockIdx.x, t = threadIdx.x;
    if (bx < 128) {
        // q part: qt_g[n][kh][bh][8]; one (n, bh) per thread
        int bh = t & 31, nn = (t >> 5) & 7;
        int n = bx * 8 + nn;
        int b = bh >> 2, h = bh & 3;
        float vals[16];
        #pragma unroll
        for (int k = 0; k < 16; ++k) {
            int ch = h * 16 + k;
            vals[k] = qkv[((size_t)b * TOTCH + ch) * NPIX + n] * sA[ch] + sB[ch];
        }
        uint4 w0, w1;
        w0.x = pk2(vals[0], vals[1]);  w0.y = pk2(vals[2], vals[3]);
        w0.z = pk2(vals[4], vals[5]);  w0.w = pk2(vals[6], vals[7]);
        w1.x = pk2(vals[8], vals[9]);  w1.y = pk2(vals[10], vals[11]);
        w1.z = pk2(vals[12], vals[13]); w1.w = pk2(vals[14], vals[15]);
        *(uint4*)&qt_g[(size_t)n * 512 + bh * 8]       = w0;
        *(uint4*)&qt_g[(size_t)n * 512 + 256 + bh * 8] = w1;
    } else if (bx < 512) {
        // v part: vt_g[b][mt][vh][vt][mq][vl][8]
        int gi = (bx - 128) * 256 + t;   // < 98304
        int m8 = gi & 127;
        int vg = (gi >> 7) % 96;
        int b  = gi / (96 * 128);
        int m  = m8 * 8;
        int row = 80 + vg;
        float a = sA[row], bb = sB[row];
        const float* p = qkv + ((size_t)b * TOTCH + row) * NPIX + m;
        float4 f0 = *(const float4*)p;
        float4 f1 = *(const float4*)(p + 4);
        uint4 w;
        w.x = pk2(f0.x * a + bb, f0.y * a + bb);
        w.y = pk2(f0.z * a + bb, f0.w * a + bb);
        w.z = pk2(f1.x * a + bb, f1.y * a + bb);
        w.w = pk2(f1.z * a + bb, f1.w * a + bb);
        int mt = m >> 5, mq = (m >> 3) & 3;
        int vhh = vg / 48, vtt = (vg % 48) >> 4, vl = vg & 15;
        size_t idx = ((((size_t)b * 32 + mt) * 2 + vhh) * 3 + vtt) * 512
                   + mq * 128 + vl * 8;
        *(uint4*)&vt_g[idx] = w;
    } else {
        // content lambda: thread t owns m in [4t, 4t+4) -> coalesced rows
        int gi = bx - 512;
        int v = gi % 96, b = gi / 96;
        int row = 80 + v;
        float a = sA[row], bb = sB[row];
        const float* vp = qkv + ((size_t)b * TOTCH + row) * NPIX;
        const float* kp = ksm + (size_t)b * 16 * NPIX;
        float4 vv = *(const float4*)(vp + t * 4);
        float4 vhat;
        vhat.x = vv.x * a + bb; vhat.y = vv.y * a + bb;
        vhat.z = vv.z * a + bb; vhat.w = vv.w * a + bb;
        float acc[16];
        #pragma unroll
        for (int k = 0; k < 16; ++k) {
            float4 kk = *(const float4*)(kp + (size_t)k * NPIX + t * 4);
            acc[k] = kk.x * vhat.x + kk.y * vhat.y
                   + kk.z * vhat.z + kk.w * vhat.w;
        }
        #pragma unroll
        for (int k = 0; k < 16; ++k) {
            #pragma unroll
            for (int off = 32; off > 0; off >>= 1)
                acc[k] += __shfl_down(acc[k], off);
        }
        __shared__ float red[16][4];
        int wid = t >> 6, lane = t & 63;
        if (lane == 0) {
            #pragma unroll
            for (int k = 0; k < 16; ++k) red[k][wid] = acc[k];
        }
        __syncthreads();
        int vhh = v / 48, vtt = (v % 48) >> 4, vl = v & 15;
        size_t plane = ((size_t)(b * 2 + vhh) * 3 + vtt) * 512;
        if (t < 16) {
            int k = t;
            float val = red[k][0] + red[k][1] + red[k][2] + red[k][3];
            lc_g[plane + (k >> 3) * 128 + vl * 8 + (k & 7)] = f2bf(val);
        } else if (t < 18) {
            int mq = 2 + (t - 16);
            uint4 z; z.x = z.y = z.z = z.w = 0u;
            *(uint4*)&lc_g[plane + mq * 128 + vl * 8] = z;
        }
    }
}

// ---------------- K4: fused MFMA lambda, 4n-per-block, pos read once --------
// r11: identical structure to r10; __launch_bounds__(512, 2) lifts the
// VGPR cap (64 -> ~256) so av/nv/pos prefetches stay in flight instead of
// serializing one load-latency at a time.
__global__ __launch_bounds__(512, 2) void k_main(const float* __restrict__ pos,
    const ushort16_t* __restrict__ qt_g, const ushort16_t* __restrict__ vt_g,
    const ushort16_t* __restrict__ lc_g, float* __restrict__ out)
{
    __shared__ __align__(16) ushort16_t S_s[2][8256];   // 2 x 16.1 KB
    int tid  = threadIdx.x;
    int lane = tid & 63;
    int wave = tid >> 6;
    int n0 = blockIdx.x * 4;

    int col1 = lane & 31, half = lane >> 5;
    int nsub = wave & 3, mc0 = wave >> 2;

    // phase-1 write addressing (lane's d column = (b,h) = (col1>>2, col1&3))
    int colw  = (col1 & 3) * 4 + nsub;            // lds col = h*4 + n
    int key3w = nsub + ((col1 & 1) << 2);         // n + 4*(h&1)
    int basew = (col1 >> 2) * 1032 + colw * 64 + half * 4;

    // phase-2 read addressing (wave = b; lane col = (h,n), k-quad)
    int b2 = wave;
    int c2 = lane & 15, kq = lane >> 4;
    int h2 = c2 >> 2, n2 = c2 & 3;
    int key3r = n2 + ((h2 & 1) << 2);
    int baser = b2 * 1032 + (h2 * 4 + n2) * 64;

    short8 qfr = *(const short8*)(qt_g + (size_t)(n0 + nsub) * 512
                                  + half * 256 + col1 * 8);

    floatx4 acc[6];
    #pragma unroll
    for (int vg = 0; vg < 6; ++vg) acc[vg] = floatx4{0.f, 0.f, 0.f, 0.f};

    floatx16 z16;
    #pragma unroll
    for (int i = 0; i < 16; ++i) z16[i] = 0.f;

    const float* pA = pos + ((size_t)(n0 + nsub) * 1024 + mc0 * 32 + col1) * 16
                    + half * 8;
    const ushort16_t* pV = vt_g + (size_t)b2 * 98304 + lane * 8;

    float4 a0c = *(const float4*)(pA);
    float4 a1c = *(const float4*)(pA + 4);
    float4 a0n = *(const float4*)(pA + 1024);
    float4 a1n = *(const float4*)(pA + 1028);

    short8 av[6];
    #pragma unroll
    for (int vg = 0; vg < 6; ++vg)              // (i=0, mc=0): mt = 0
        av[vg] = *(const short8*)(pV + vg * 512);

    for (int i = 0; i < 16; ++i) {
        // issue this iter's mc=1 v-fragments early (mt = 2i+1)
        short8 nv[6];
        #pragma unroll
        for (int vg = 0; vg < 6; ++vg)
            nv[vg] = *(const short8*)(pV + (size_t)(2 * i + 1) * 3072
                                         + vg * 512);
        float4 a0nn, a1nn;
        if (i < 14) {
            const float* p = pA + (size_t)(i + 2) * 1024;
            a0nn = *(const float4*)p;
            a1nn = *(const float4*)(p + 4);
        }
        // ---- phase 1: P[m32, (b,h)32] for (nsub, mc0) ----
        {
            uint4 aw;
            aw.x = pk2(a0c.x, a0c.y); aw.y = pk2(a0c.z, a0c.w);
            aw.z = pk2(a1c.x, a1c.y); aw.w = pk2(a1c.z, a1c.w);
            short8 afr = *(short8*)&aw;
            floatx16 d = __builtin_amdgcn_mfma_f32_32x32x16_bf16(
                afr, qfr, z16, 0, 0, 0);
            ushort16_t* Sb = S_s[i & 1];
            #pragma unroll
            for (int q = 0; q < 4; ++q) {
                int slot = (mc0 * 4 + q) ^ key3w;
                uint2 wv;
                wv.x = pk2(d[q * 4 + 0], d[q * 4 + 1]);
                wv.y = pk2(d[q * 4 + 2], d[q * 4 + 3]);
                *(uint2*)&Sb[basew + slot * 8] = wv;
            }
        }
        __builtin_amdgcn_s_waitcnt(LGKM0_ONLY);
        __builtin_amdgcn_s_barrier();
        {
            const ushort16_t* Sr = S_s[i & 1];
            // ---- mc = 0 ----
            short8 bs0 = *(const short8*)&Sr[baser + (kq ^ key3r) * 8];
            #pragma unroll
            for (int vg = 0; vg < 6; ++vg)
                acc[vg] = __builtin_amdgcn_mfma_f32_16x16x32_bf16(
                    av[vg], bs0, acc[vg], 0, 0, 0);
            // prefetch next-iter mc=0 (mt = 2i+2)
            if (i < 15) {
                #pragma unroll
                for (int vg = 0; vg < 6; ++vg)
                    av[vg] = *(const short8*)(pV + (size_t)(2 * i + 2) * 3072
                                                 + vg * 512);
            }
            // ---- mc = 1 ----
            short8 bs1 = *(const short8*)&Sr[baser + ((4 + kq) ^ key3r) * 8];
            #pragma unroll
            for (int vg = 0; vg < 6; ++vg)
                acc[vg] = __builtin_amdgcn_mfma_f32_16x16x32_bf16(
                    nv[vg], bs1, acc[vg], 0, 0, 0);
        }
        a0c = a0n; a1c = a1n;
        if (i < 14) { a0n = a0nn; a1n = a1nn; }
    }

    // ---- content-lambda extension (pure-register, no LDS) ----
    {
        short8 bsq = {0, 0, 0, 0, 0, 0, 0, 0};
        if (kq < 2)
            bsq = *(const short8*)(qt_g + (size_t)(n0 + n2) * 512
                                   + kq * 256 + (b2 * 4 + h2) * 8);
        const ushort16_t* lsrc = lc_g + (size_t)b2 * 3072 + lane * 8;
        #pragma unroll
        for (int vg = 0; vg < 6; ++vg) {
            short8 lv = *(const short8*)(lsrc + vg * 512);
            acc[vg] = __builtin_amdgcn_mfma_f32_16x16x32_bf16(
                lv, bsq, acc[vg], 0, 0, 0);
        }
    }

    // ---- epilogue: plain stores, each out element written exactly once ----
    {
        #pragma unroll
        for (int vg = 0; vg < 6; ++vg) {
            int vbase = (vg / 3) * 48 + (vg % 3) * 16 + kq * 4;
            #pragma unroll
            for (int r = 0; r < 4; ++r) {
                int v = vbase + r;
                out[(size_t)(b2 * 384 + h2 * 96 + v) * 1024 + n0 + n2]
                    = acc[vg][r];
            }
        }
    }
}

extern "C" void kernel_launch(void* const* d_in, const int* in_sizes, int n_in,
                              void* d_out, int out_size, void* d_ws, size_t ws_size,
                              hipStream_t stream) {
    const float* x   = (const float*)d_in[0];
    const float* Wq  = (const float*)d_in[1];
    const float* Wk  = (const float*)d_in[2];
    const float* Wv  = (const float*)d_in[3];
    const float* gq  = (const float*)d_in[4];
    const float* bq  = (const float*)d_in[5];
    const float* gv  = (const float*)d_in[6];
    const float* bv  = (const float*)d_in[7];
    const float* pos = (const float*)d_in[8];
    float* out = (float*)d_out;
    float* ws  = (float*)d_ws;

    float* qkv = ws;
    float* sA  = ws + 1441792;
    float* sB  = ws + 1441968;
    float* ksm = ws + 1442144;
    ushort16_t* qt_g = (ushort16_t*)(ws + 1573216);
    ushort16_t* vt_g = (ushort16_t*)(ws + 1835360);
    ushort16_t* lc_g = (ushort16_t*)(ws + 2228576);
    ushort16_t* wbf  = (ushort16_t*)(ws + 3813728);

    k_wt<<<dim3(4), dim3(256), 0, stream>>>(Wq, Wk, Wv, wbf);
    k_proj<<<dim3(256), dim3(256), 0, stream>>>(x, wbf, qkv);
    k_bnsm<<<dim3(288), dim3(256), 0, stream>>>(qkv, gq, bq, gv, bv, sA, sB, ksm);
    k_packlc<<<dim3(1280), dim3(256), 0, stream>>>(qkv, sA, sB, ksm,
                                                   qt_g, vt_g, lc_g);
    k_main<<<dim3(256), dim3(512), 0, stream>>>(pos, qt_g, vt_g, lc_g, out);
}

// Round 5
// 170.654 us; speedup vs baseline: 1.0483x; 1.0483x over previous
//
#include <hip/hip_runtime.h>

typedef __attribute__((ext_vector_type(8))) short short8;
typedef __attribute__((ext_vector_type(16))) float floatx16;
typedef __attribute__((ext_vector_type(4))) float floatx4;
typedef unsigned short ushort16_t;
typedef unsigned int uint32;

#define BB 8
#define CC 384
#define NPIX 1024
#define TOTCH 176      // 64 q + 16 k + 96 v
#define BN_EPS 1e-5f

// ---------- helpers ----------
__device__ __forceinline__ ushort16_t f2bf(float x) {
    uint32 u = __float_as_uint(x);
    u += 0x7FFFu + ((u >> 16) & 1u);
    return (ushort16_t)(u >> 16);
}
__device__ __forceinline__ uint32 pk2(float a, float b) {
    uint32 ua = __float_as_uint(a); ua += 0x7FFFu + ((ua >> 16) & 1u);
    uint32 ub = __float_as_uint(b); ub += 0x7FFFu + ((ub >> 16) & 1u);
    return (ua >> 16) | (ub & 0xFFFF0000u);
}
__device__ __forceinline__ int div48(int x) {   // valid for x < 16384
    return (int)(((unsigned)x * 21846u) >> 20);
}
// lgkmcnt(0), vmcnt unconstrained (63), expcnt unconstrained (7)
#define LGKM0_ONLY 0xC07F

// issue-pinned global loads: volatile asm preserves program order among
// volatile ops, so the scheduler cannot sink these to their use sites.
__device__ __forceinline__ void gload8h(short8 &d, const ushort16_t* p) {
    asm volatile("global_load_dwordx4 %0, %1, off" : "=v"(d) : "v"(p));
}
__device__ __forceinline__ void gload4f(float4 &d, const float* p) {
    asm volatile("global_load_dwordx4 %0, %1, off" : "=v"(d) : "v"(p));
}

// ws layout (float units):
// qkv  [B][176][N]        @ 0         (1441792)
// sA   [176]              @ 1441792
// sB   [176]              @ 1441968
// ksm  [B][16][N]         @ 1442144   (131072)
// qt_g bf16 [n][kh2][bh32][8]                 @f 1573216 (262144 f)
// vt_g bf16 [b][mt32][vh2][vt3][mq4][v16][8]  @f 1835360 (393216 f)
// lc_g bf16 [b][vh2][vt3][mq4][v16][8]        @f 2228576 (12288 f)
// wbf  bf16 [row192][c384]                    @f 3813728 (36864 f)

// ---------------- K0: W -> bf16 wbf (tiny) ----------------------------------
__global__ __launch_bounds__(256, 2) void k_wt(const float* __restrict__ Wq,
    const float* __restrict__ Wk, const float* __restrict__ Wv,
    ushort16_t* __restrict__ wbf)
{
    int bx = blockIdx.x, t = threadIdx.x;
    #pragma unroll
    for (int jj = 0; jj < 9; ++jj) {
        int idx8 = (bx * 9 + jj) * 256 + t;   // [0, 9216)
        int row = div48(idx8);
        int g   = idx8 - row * 48;
        float4 f0, f1;
        if (row < 176) {
            const float* src;
            if (row < 64)       src = Wq + (size_t)row * CC;
            else if (row < 80)  src = Wk + (size_t)(row - 64) * CC;
            else                src = Wv + (size_t)(row - 80) * CC;
            f0 = *(const float4*)(src + g * 8);
            f1 = *(const float4*)(src + g * 8 + 4);
        } else {
            f0.x = f0.y = f0.z = f0.w = 0.f;
            f1 = f0;
        }
        uint4 w;
        w.x = pk2(f0.x, f0.y); w.y = pk2(f0.z, f0.w);
        w.z = pk2(f1.x, f1.y); w.w = pk2(f1.z, f1.w);
        *(uint4*)&wbf[(size_t)row * CC + g * 8] = w;
    }
}

// ---------------- K1: fused transpose + q/k/v projection (MFMA) -------------
__global__ __launch_bounds__(256, 2) void k_proj(const float* __restrict__ x,
    const ushort16_t* __restrict__ wbf, float* __restrict__ qkv)
{
    __shared__ __align__(16) ushort16_t XT[32 * 392];  // 24.5 KB, pad 392
    int bx = blockIdx.x, t = threadIdx.x;
    int b = bx >> 5, nbase = (bx & 31) * 32;
    const float* xb = x + (size_t)b * (CC * NPIX) + nbase;
    #pragma unroll
    for (int j = 0; j < 12; ++j) {
        int idx = t + 256 * j;           // [0, 3072) = 384 c x 8 n-groups
        int c = idx >> 3, ng = idx & 7;
        float4 f = *(const float4*)(xb + (size_t)c * NPIX + ng * 4);
        int col = ng * 4;
        XT[(col + 0) * 392 + c] = f2bf(f.x);
        XT[(col + 1) * 392 + c] = f2bf(f.y);
        XT[(col + 2) * 392 + c] = f2bf(f.z);
        XT[(col + 3) * 392 + c] = f2bf(f.w);
    }
    __syncthreads();

    int wave = t >> 6, lane = t & 63;
    int ct = wave & 1;            // col-tile (16 cols)
    int rs = wave >> 1;           // row-tile parity
    int col1 = lane & 15, kq = lane >> 4;
    const ushort16_t* bbase = &XT[(ct * 16 + col1) * 392 + kq * 8];
    int n = nbase + ct * 16 + col1;

    for (int r = rs; r < 11; r += 2) {
        int r0 = r * 16;
        const ushort16_t* ap = wbf + (size_t)(r0 + col1) * CC + kq * 8;
        floatx4 acc = {0.f, 0.f, 0.f, 0.f};
        short8 a0 = *(const short8*)ap;
        short8 b0 = *(const short8*)bbase;
        #pragma unroll
        for (int k = 1; k < 12; ++k) {
            short8 a1 = *(const short8*)(ap + k * 32);
            short8 b1 = *(const short8*)(bbase + k * 32);
            acc = __builtin_amdgcn_mfma_f32_16x16x32_bf16(a0, b0, acc, 0, 0, 0);
            a0 = a1; b0 = b1;
        }
        acc = __builtin_amdgcn_mfma_f32_16x16x32_bf16(a0, b0, acc, 0, 0, 0);
        #pragma unroll
        for (int rr = 0; rr < 4; ++rr) {
            int ch = r0 + kq * 4 + rr;
            qkv[((size_t)b * TOTCH + ch) * NPIX + n] = acc[rr];
        }
    }
}

// ---------------- K2: BN stats + softmax (merged, float4) -------------------
__global__ __launch_bounds__(256, 2) void k_bnsm(const float* __restrict__ qkv,
    const float* __restrict__ gq, const float* __restrict__ bq,
    const float* __restrict__ gv, const float* __restrict__ bv,
    float* __restrict__ sA, float* __restrict__ sB, float* __restrict__ ksm)
{
    int bx = blockIdx.x, tid = threadIdx.x;
    int wid = tid >> 6, lane = tid & 63;
    if (bx < 160) {
        int ch = bx;
        int row; float gamma, beta;
        if (ch < 64) { row = ch; gamma = gq[ch]; beta = bq[ch]; }
        else { int j = ch - 64; row = 80 + j; gamma = gv[j]; beta = bv[j]; }
        float s = 0.f, ss = 0.f;
        #pragma unroll
        for (int j = 0; j < 8; ++j) {
            int i4 = tid + 256 * j;
            int b = i4 >> 8, n4 = i4 & 255;
            float4 f = *(const float4*)(qkv + ((size_t)b * TOTCH + row) * NPIX
                                            + n4 * 4);
            s  += f.x + f.y + f.z + f.w;
            ss += f.x * f.x + f.y * f.y + f.z * f.z + f.w * f.w;
        }
        #pragma unroll
        for (int off = 32; off > 0; off >>= 1) {
            s  += __shfl_down(s, off);
            ss += __shfl_down(ss, off);
        }
        __shared__ float rs[4], rss[4];
        if (lane == 0) { rs[wid] = s; rss[wid] = ss; }
        __syncthreads();
        if (tid == 0) {
            float S  = rs[0] + rs[1] + rs[2] + rs[3];
            float SS = rss[0] + rss[1] + rss[2] + rss[3];
            float inv = 1.f / (BB * NPIX);
            float mean = S * inv;
            float var  = SS * inv - mean * mean;
            float a = gamma * rsqrtf(var + BN_EPS);
            sA[row] = a;
            sB[row] = beta - mean * a;
        }
    } else {
        int idx = bx - 160;
        int kc = idx & 15, b = idx >> 4;
        const float* rowp = qkv + ((size_t)b * TOTCH + 64 + kc) * NPIX;
        float4 v4 = *(const float4*)(rowp + tid * 4);
        float v[4] = {v4.x, v4.y, v4.z, v4.w};
        float mx = fmaxf(fmaxf(v[0], v[1]), fmaxf(v[2], v[3]));
        #pragma unroll
        for (int off = 32; off > 0; off >>= 1) mx = fmaxf(mx, __shfl_down(mx, off));
        __shared__ float sm[4], ssum[4];
        if (lane == 0) sm[wid] = mx;
        __syncthreads();
        mx = fmaxf(fmaxf(sm[0], sm[1]), fmaxf(sm[2], sm[3]));
        float e[4], s = 0.f;
        #pragma unroll
        for (int j = 0; j < 4; ++j) { e[j] = __expf(v[j] - mx); s += e[j]; }
        #pragma unroll
        for (int off = 32; off > 0; off >>= 1) s += __shfl_down(s, off);
        if (lane == 0) ssum[wid] = s;
        __syncthreads();
        float inv = 1.f / (ssum[0] + ssum[1] + ssum[2] + ssum[3]);
        float4 o;
        o.x = e[0] * inv; o.y = e[1] * inv; o.z = e[2] * inv; o.w = e[3] * inv;
        *(float4*)(ksm + ((size_t)b * 16 + kc) * NPIX + tid * 4) = o;
    }
}

// ---------------- K3: pack q/v (bf16 tiled) + content lambda (fused) --------
__global__ __launch_bounds__(256, 2) void k_packlc(const float* __restrict__ qkv,
    const float* __restrict__ sA, const float* __restrict__ sB,
    const float* __restrict__ ksm,
    ushort16_t* __restrict__ qt_g, ushort16_t* __restrict__ vt_g,
    ushort16_t* __restrict__ lc_g)
{
    int bx = blockIdx.x, t = threadIdx.x;
    if (bx < 128) {
        // q part: qt_g[n][kh][bh][8]; one (n, bh) per thread
        int bh = t & 31, nn = (t >> 5) & 7;
        int n = bx * 8 + nn;
        int b = bh >> 2, h = bh & 3;
        float vals[16];
        #pragma unroll
        for (int k = 0; k < 16; ++k) {
            int ch = h * 16 + k;
            vals[k] = qkv[((size_t)b * TOTCH + ch) * NPIX + n] * sA[ch] + sB[ch];
        }
        uint4 w0, w1;
        w0.x = pk2(vals[0], vals[1]);  w0.y = pk2(vals[2], vals[3]);
        w0.z = pk2(vals[4], vals[5]);  w0.w = pk2(vals[6], vals[7]);
        w1.x = pk2(vals[8], vals[9]);  w1.y = pk2(vals[10], vals[11]);
        w1.z = pk2(vals[12], vals[13]); w1.w = pk2(vals[14], vals[15]);
        *(uint4*)&qt_g[(size_t)n * 512 + bh * 8]       = w0;
        *(uint4*)&qt_g[(size_t)n * 512 + 256 + bh * 8] = w1;
    } else if (bx < 512) {
        // v part: vt_g[b][mt][vh][vt][mq][vl][8]
        int gi = (bx - 128) * 256 + t;   // < 98304
        int m8 = gi & 127;
        int vg = (gi >> 7) % 96;
        int b  = gi / (96 * 128);
        int m  = m8 * 8;
        int row = 80 + vg;
        float a = sA[row], bb = sB[row];
        const float* p = qkv + ((size_t)b * TOTCH + row) * NPIX + m;
        float4 f0 = *(const float4*)p;
        float4 f1 = *(const float4*)(p + 4);
        uint4 w;
        w.x = pk2(f0.x * a + bb, f0.y * a + bb);
        w.y = pk2(f0.z * a + bb, f0.w * a + bb);
        w.z = pk2(f1.x * a + bb, f1.y * a + bb);
        w.w = pk2(f1.z * a + bb, f1.w * a + bb);
        int mt = m >> 5, mq = (m >> 3) & 3;
        int vhh = vg / 48, vtt = (vg % 48) >> 4, vl = vg & 15;
        size_t idx = ((((size_t)b * 32 + mt) * 2 + vhh) * 3 + vtt) * 512
                   + mq * 128 + vl * 8;
        *(uint4*)&vt_g[idx] = w;
    } else {
        // content lambda: thread t owns m in [4t, 4t+4) -> coalesced rows
        int gi = bx - 512;
        int v = gi % 96, b = gi / 96;
        int row = 80 + v;
        float a = sA[row], bb = sB[row];
        const float* vp = qkv + ((size_t)b * TOTCH + row) * NPIX;
        const float* kp = ksm + (size_t)b * 16 * NPIX;
        float4 vv = *(const float4*)(vp + t * 4);
        float4 vhat;
        vhat.x = vv.x * a + bb; vhat.y = vv.y * a + bb;
        vhat.z = vv.z * a + bb; vhat.w = vv.w * a + bb;
        float acc[16];
        #pragma unroll
        for (int k = 0; k < 16; ++k) {
            float4 kk = *(const float4*)(kp + (size_t)k * NPIX + t * 4);
            acc[k] = kk.x * vhat.x + kk.y * vhat.y
                   + kk.z * vhat.z + kk.w * vhat.w;
        }
        #pragma unroll
        for (int k = 0; k < 16; ++k) {
            #pragma unroll
            for (int off = 32; off > 0; off >>= 1)
                acc[k] += __shfl_down(acc[k], off);
        }
        __shared__ float red[16][4];
        int wid = t >> 6, lane = t & 63;
        if (lane == 0) {
            #pragma unroll
            for (int k = 0; k < 16; ++k) red[k][wid] = acc[k];
        }
        __syncthreads();
        int vhh = v / 48, vtt = (v % 48) >> 4, vl = v & 15;
        size_t plane = ((size_t)(b * 2 + vhh) * 3 + vtt) * 512;
        if (t < 16) {
            int k = t;
            float val = red[k][0] + red[k][1] + red[k][2] + red[k][3];
            lc_g[plane + (k >> 3) * 128 + vl * 8 + (k & 7)] = f2bf(val);
        } else if (t < 18) {
            int mq = 2 + (t - 16);
            uint4 z; z.x = z.y = z.z = z.w = 0u;
            *(uint4*)&lc_g[plane + mq * 128 + vl * 8] = z;
        }
    }
}

// ---------------- K4: fused MFMA lambda, asm-pinned load pipeline (r12) -----
// Same geometry as r10 (4n/block, pos read once). All v/pos loads issued via
// volatile asm at controlled points; one counted s_waitcnt vmcnt per iter
// (never drains the 2 in-flight pos loads). sched_barrier(0) after each wait
// keeps the MFMAs from hoisting above it (rule: asm waits don't order
// register-only MFMAs).
__global__ __launch_bounds__(512, 2) void k_main(const float* __restrict__ pos,
    const ushort16_t* __restrict__ qt_g, const ushort16_t* __restrict__ vt_g,
    const ushort16_t* __restrict__ lc_g, float* __restrict__ out)
{
    __shared__ __align__(16) ushort16_t S_s[2][8256];   // 2 x 16.1 KB
    int tid  = threadIdx.x;
    int lane = tid & 63;
    int wave = tid >> 6;
    int n0 = blockIdx.x * 4;

    int col1 = lane & 31, half = lane >> 5;
    int nsub = wave & 3, mc0 = wave >> 2;

    // phase-1 write addressing
    int colw  = (col1 & 3) * 4 + nsub;            // lds col = h*4 + n
    int key3w = nsub + ((col1 & 1) << 2);         // n + 4*(h&1)
    int basew = (col1 >> 2) * 1032 + colw * 64 + half * 4;

    // phase-2 read addressing (wave = b; lane col = (h,n), k-quad)
    int b2 = wave;
    int c2 = lane & 15, kq = lane >> 4;
    int h2 = c2 >> 2, n2 = c2 & 3;
    int key3r = n2 + ((h2 & 1) << 2);
    int baser = b2 * 1032 + (h2 * 4 + n2) * 64;

    short8 qfr = *(const short8*)(qt_g + (size_t)(n0 + nsub) * 512
                                  + half * 256 + col1 * 8);

    floatx4 acc[6];
    #pragma unroll
    for (int vg = 0; vg < 6; ++vg) acc[vg] = floatx4{0.f, 0.f, 0.f, 0.f};

    floatx16 z16;
    #pragma unroll
    for (int i = 0; i < 16; ++i) z16[i] = 0.f;

    const float* pA = pos + ((size_t)(n0 + nsub) * 1024 + mc0 * 32 + col1) * 16
                    + half * 8;
    const ushort16_t* pV = vt_g + (size_t)b2 * 98304 + lane * 8;

    // pos double-slot: slot j holds pos for iteration with (i&1)==j.
    float4 pa[2], pb[2];
    gload4f(pa[0], pA);
    gload4f(pb[0], pA + 4);
    gload4f(pa[1], pA + 1024);
    gload4f(pb[1], pA + 1028);

    short8 vbuf[12];

    #pragma unroll
    for (int i = 0; i < 16; ++i) {
        // issue this iteration's 12 v-fragments (mt = 2i, 2i+1)
        const ushort16_t* pVi = pV + (size_t)i * 6144;
        #pragma unroll
        for (int vg = 0; vg < 6; ++vg)
            gload8h(vbuf[vg], pVi + vg * 512);
        #pragma unroll
        for (int vg = 0; vg < 6; ++vg)
            gload8h(vbuf[6 + vg], pVi + 3072 + vg * 512);

        if (i == 0) {   // ensure iter-0 pos arrived (leaves pos1 + v0 in flight)
            asm volatile("s_waitcnt vmcnt(14)");
            __builtin_amdgcn_sched_barrier(0);
        }

        // ---- phase 1: P[m32, (b,h)32] for (nsub, mc0) ----
        {
            float4 a0c = pa[i & 1], a1c = pb[i & 1];
            uint4 aw;
            aw.x = pk2(a0c.x, a0c.y); aw.y = pk2(a0c.z, a0c.w);
            aw.z = pk2(a1c.x, a1c.y); aw.w = pk2(a1c.z, a1c.w);
            short8 afr = *(short8*)&aw;
            floatx16 d = __builtin_amdgcn_mfma_f32_32x32x16_bf16(
                afr, qfr, z16, 0, 0, 0);
            ushort16_t* Sb = S_s[i & 1];
            #pragma unroll
            for (int q = 0; q < 4; ++q) {
                int slot = (mc0 * 4 + q) ^ key3w;
                uint2 wv;
                wv.x = pk2(d[q * 4 + 0], d[q * 4 + 1]);
                wv.y = pk2(d[q * 4 + 2], d[q * 4 + 3]);
                *(uint2*)&Sb[basew + slot * 8] = wv;
            }
        }

        // refill the just-consumed pos slot for iteration i+2
        if (i < 14) {
            const float* p = pA + (size_t)(i + 2) * 1024;
            gload4f(pa[i & 1], p);
            gload4f(pb[i & 1], p + 4);
        }

        __builtin_amdgcn_s_waitcnt(LGKM0_ONLY);
        __builtin_amdgcn_s_barrier();

        // counted wait: v-loads of this iter done; pos loads stay in flight
        if (i < 14) asm volatile("s_waitcnt vmcnt(2)");
        else        asm volatile("s_waitcnt vmcnt(0)");
        __builtin_amdgcn_sched_barrier(0);

        // ---- phase 2 ----
        {
            const ushort16_t* Sr = S_s[i & 1];
            short8 bs0 = *(const short8*)&Sr[baser + (kq ^ key3r) * 8];
            #pragma unroll
            for (int vg = 0; vg < 6; ++vg)
                acc[vg] = __builtin_amdgcn_mfma_f32_16x16x32_bf16(
                    vbuf[vg], bs0, acc[vg], 0, 0, 0);
            short8 bs1 = *(const short8*)&Sr[baser + ((4 + kq) ^ key3r) * 8];
            #pragma unroll
            for (int vg = 0; vg < 6; ++vg)
                acc[vg] = __builtin_amdgcn_mfma_f32_16x16x32_bf16(
                    vbuf[6 + vg], bs1, acc[vg], 0, 0, 0);
        }
    }

    // ---- content-lambda extension (pure-register, no LDS) ----
    {
        short8 bsq = {0, 0, 0, 0, 0, 0, 0, 0};
        if (kq < 2)
            bsq = *(const short8*)(qt_g + (size_t)(n0 + n2) * 512
                                   + kq * 256 + (b2 * 4 + h2) * 8);
        const ushort16_t* lsrc = lc_g + (size_t)b2 * 3072 + lane * 8;
        #pragma unroll
        for (int vg = 0; vg < 6; ++vg) {
            short8 lv = *(const short8*)(lsrc + vg * 512);
            acc[vg] = __builtin_amdgcn_mfma_f32_16x16x32_bf16(
                lv, bsq, acc[vg], 0, 0, 0);
        }
    }

    // ---- epilogue: plain stores, each out element written exactly once ----
    {
        #pragma unroll
        for (int vg = 0; vg < 6; ++vg) {
            int vbase = (vg / 3) * 48 + (vg % 3) * 16 + kq * 4;
            #pragma unroll
            for (int r = 0; r < 4; ++r) {
                int v = vbase + r;
                out[(size_t)(b2 * 384 + h2 * 96 + v) * 1024 + n0 + n2]
                    = acc[vg][r];
            }
        }
    }
}

extern "C" void kernel_launch(void* const* d_in, const int* in_sizes, int n_in,
                              void* d_out, int out_size, void* d_ws, size_t ws_size,
                              hipStream_t stream) {
    const float* x   = (const float*)d_in[0];
    const float* Wq  = (const float*)d_in[1];
    const float* Wk  = (const float*)d_in[2];
    const float* Wv  = (const float*)d_in[3];
    const float* gq  = (const float*)d_in[4];
    const float* bq  = (const float*)d_in[5];
    const float* gv  = (const float*)d_in[6];
    const float* bv  = (const float*)d_in[7];
    const float* pos = (const float*)d_in[8];
    float* out = (float*)d_out;
    float* ws  = (float*)d_ws;

    float* qkv = ws;
    float* sA  = ws + 1441792;
    float* sB  = ws + 1441968;
    float* ksm = ws + 1442144;
    ushort16_t* qt_g = (ushort16_t*)(ws + 1573216);
    ushort16_t* vt_g = (ushort16_t*)(ws + 1835360);
    ushort16_t* lc_g = (ushort16_t*)(ws + 2228576);
    ushort16_t* wbf  = (ushort16_t*)(ws + 3813728);

    k_wt<<<dim3(4), dim3(256), 0, stream>>>(Wq, Wk, Wv, wbf);
    k_proj<<<dim3(256), dim3(256), 0, stream>>>(x, wbf, qkv);
    k_bnsm<<<dim3(288), dim3(256), 0, stream>>>(qkv, gq, bq, gv, bv, sA, sB, ksm);
    k_packlc<<<dim3(1280), dim3(256), 0, stream>>>(qkv, sA, sB, ksm,
                                                   qt_g, vt_g, lc_g);
    k_main<<<dim3(256), dim3(512), 0, stream>>>(pos, qt_g, vt_g, lc_g, out);
}

// Round 6
// 169.508 us; speedup vs baseline: 1.0554x; 1.0068x over previous
//
#include <hip/hip_runtime.h>

typedef __attribute__((ext_vector_type(8))) short short8;
typedef __attribute__((ext_vector_type(16))) float floatx16;
typedef __attribute__((ext_vector_type(4))) float floatx4;
typedef unsigned short ushort16_t;
typedef unsigned int uint32;

#define BB 8
#define CC 384
#define NPIX 1024
#define TOTCH 176      // 64 q + 16 k + 96 v
#define BN_EPS 1e-5f

// ---------- helpers ----------
__device__ __forceinline__ ushort16_t f2bf(float x) {
    uint32 u = __float_as_uint(x);
    u += 0x7FFFu + ((u >> 16) & 1u);
    return (ushort16_t)(u >> 16);
}
__device__ __forceinline__ uint32 pk2(float a, float b) {
    uint32 ua = __float_as_uint(a); ua += 0x7FFFu + ((ua >> 16) & 1u);
    uint32 ub = __float_as_uint(b); ub += 0x7FFFu + ((ub >> 16) & 1u);
    return (ua >> 16) | (ub & 0xFFFF0000u);
}
__device__ __forceinline__ int div48(int x) {   // valid for x < 16384
    return (int)(((unsigned)x * 21846u) >> 20);
}
// lgkmcnt(0), vmcnt unconstrained (63), expcnt unconstrained (7)
#define LGKM0_ONLY 0xC07F

// issue-pinned global loads: volatile asm preserves program order among
// volatile ops, so the scheduler cannot sink these to their use sites.
__device__ __forceinline__ void gload8h(short8 &d, const ushort16_t* p) {
    asm volatile("global_load_dwordx4 %0, %1, off" : "=v"(d) : "v"(p));
}
__device__ __forceinline__ void gload4f(float4 &d, const float* p) {
    asm volatile("global_load_dwordx4 %0, %1, off" : "=v"(d) : "v"(p));
}

// ws layout (float units):
// qkv  [B][176][N]        @ 0         (1441792)
// sA   [176]              @ 1441792
// sB   [176]              @ 1441968
// ksm  [B][16][N]         @ 1442144   (131072)
// qt_g bf16 [n][kh2][bh32][8]                 @f 1573216 (262144 f)
// vt_g bf16 [b][mt32][vh2][vt3][mq4][v16][8]  @f 1835360 (393216 f)
// lc_g bf16 [b][vh2][vt3][mq4][v16][8]        @f 2228576 (12288 f)
// wbf  bf16 [row192][c384]                    @f 3813728 (36864 f)

// ---------------- K0: W -> bf16 wbf (tiny) ----------------------------------
__global__ __launch_bounds__(256, 2) void k_wt(const float* __restrict__ Wq,
    const float* __restrict__ Wk, const float* __restrict__ Wv,
    ushort16_t* __restrict__ wbf)
{
    int bx = blockIdx.x, t = threadIdx.x;
    #pragma unroll
    for (int jj = 0; jj < 9; ++jj) {
        int idx8 = (bx * 9 + jj) * 256 + t;   // [0, 9216)
        int row = div48(idx8);
        int g   = idx8 - row * 48;
        float4 f0, f1;
        if (row < 176) {
            const float* src;
            if (row < 64)       src = Wq + (size_t)row * CC;
            else if (row < 80)  src = Wk + (size_t)(row - 64) * CC;
            else                src = Wv + (size_t)(row - 80) * CC;
            f0 = *(const float4*)(src + g * 8);
            f1 = *(const float4*)(src + g * 8 + 4);
        } else {
            f0.x = f0.y = f0.z = f0.w = 0.f;
            f1 = f0;
        }
        uint4 w;
        w.x = pk2(f0.x, f0.y); w.y = pk2(f0.z, f0.w);
        w.z = pk2(f1.x, f1.y); w.w = pk2(f1.z, f1.w);
        *(uint4*)&wbf[(size_t)row * CC + g * 8] = w;
    }
}

// ---------------- K1: fused transpose + q/k/v projection (MFMA) -------------
__global__ __launch_bounds__(256, 2) void k_proj(const float* __restrict__ x,
    const ushort16_t* __restrict__ wbf, float* __restrict__ qkv)
{
    __shared__ __align__(16) ushort16_t XT[32 * 392];  // 24.5 KB, pad 392
    int bx = blockIdx.x, t = threadIdx.x;
    int b = bx >> 5, nbase = (bx & 31) * 32;
    const float* xb = x + (size_t)b * (CC * NPIX) + nbase;
    #pragma unroll
    for (int j = 0; j < 12; ++j) {
        int idx = t + 256 * j;           // [0, 3072) = 384 c x 8 n-groups
        int c = idx >> 3, ng = idx & 7;
        float4 f = *(const float4*)(xb + (size_t)c * NPIX + ng * 4);
        int col = ng * 4;
        XT[(col + 0) * 392 + c] = f2bf(f.x);
        XT[(col + 1) * 392 + c] = f2bf(f.y);
        XT[(col + 2) * 392 + c] = f2bf(f.z);
        XT[(col + 3) * 392 + c] = f2bf(f.w);
    }
    __syncthreads();

    int wave = t >> 6, lane = t & 63;
    int ct = wave & 1;            // col-tile (16 cols)
    int rs = wave >> 1;           // row-tile parity
    int col1 = lane & 15, kq = lane >> 4;
    const ushort16_t* bbase = &XT[(ct * 16 + col1) * 392 + kq * 8];
    int n = nbase + ct * 16 + col1;

    for (int r = rs; r < 11; r += 2) {
        int r0 = r * 16;
        const ushort16_t* ap = wbf + (size_t)(r0 + col1) * CC + kq * 8;
        floatx4 acc = {0.f, 0.f, 0.f, 0.f};
        short8 a0 = *(const short8*)ap;
        short8 b0 = *(const short8*)bbase;
        #pragma unroll
        for (int k = 1; k < 12; ++k) {
            short8 a1 = *(const short8*)(ap + k * 32);
            short8 b1 = *(const short8*)(bbase + k * 32);
            acc = __builtin_amdgcn_mfma_f32_16x16x32_bf16(a0, b0, acc, 0, 0, 0);
            a0 = a1; b0 = b1;
        }
        acc = __builtin_amdgcn_mfma_f32_16x16x32_bf16(a0, b0, acc, 0, 0, 0);
        #pragma unroll
        for (int rr = 0; rr < 4; ++rr) {
            int ch = r0 + kq * 4 + rr;
            qkv[((size_t)b * TOTCH + ch) * NPIX + n] = acc[rr];
        }
    }
}

// ---------------- K2: BN stats + softmax (merged, float4) -------------------
__global__ __launch_bounds__(256, 2) void k_bnsm(const float* __restrict__ qkv,
    const float* __restrict__ gq, const float* __restrict__ bq,
    const float* __restrict__ gv, const float* __restrict__ bv,
    float* __restrict__ sA, float* __restrict__ sB, float* __restrict__ ksm)
{
    int bx = blockIdx.x, tid = threadIdx.x;
    int wid = tid >> 6, lane = tid & 63;
    if (bx < 160) {
        int ch = bx;
        int row; float gamma, beta;
        if (ch < 64) { row = ch; gamma = gq[ch]; beta = bq[ch]; }
        else { int j = ch - 64; row = 80 + j; gamma = gv[j]; beta = bv[j]; }
        float s = 0.f, ss = 0.f;
        #pragma unroll
        for (int j = 0; j < 8; ++j) {
            int i4 = tid + 256 * j;
            int b = i4 >> 8, n4 = i4 & 255;
            float4 f = *(const float4*)(qkv + ((size_t)b * TOTCH + row) * NPIX
                                            + n4 * 4);
            s  += f.x + f.y + f.z + f.w;
            ss += f.x * f.x + f.y * f.y + f.z * f.z + f.w * f.w;
        }
        #pragma unroll
        for (int off = 32; off > 0; off >>= 1) {
            s  += __shfl_down(s, off);
            ss += __shfl_down(ss, off);
        }
        __shared__ float rs[4], rss[4];
        if (lane == 0) { rs[wid] = s; rss[wid] = ss; }
        __syncthreads();
        if (tid == 0) {
            float S  = rs[0] + rs[1] + rs[2] + rs[3];
            float SS = rss[0] + rss[1] + rss[2] + rss[3];
            float inv = 1.f / (BB * NPIX);
            float mean = S * inv;
            float var  = SS * inv - mean * mean;
            float a = gamma * rsqrtf(var + BN_EPS);
            sA[row] = a;
            sB[row] = beta - mean * a;
        }
    } else {
        int idx = bx - 160;
        int kc = idx & 15, b = idx >> 4;
        const float* rowp = qkv + ((size_t)b * TOTCH + 64 + kc) * NPIX;
        float4 v4 = *(const float4*)(rowp + tid * 4);
        float v[4] = {v4.x, v4.y, v4.z, v4.w};
        float mx = fmaxf(fmaxf(v[0], v[1]), fmaxf(v[2], v[3]));
        #pragma unroll
        for (int off = 32; off > 0; off >>= 1) mx = fmaxf(mx, __shfl_down(mx, off));
        __shared__ float sm[4], ssum[4];
        if (lane == 0) sm[wid] = mx;
        __syncthreads();
        mx = fmaxf(fmaxf(sm[0], sm[1]), fmaxf(sm[2], sm[3]));
        float e[4], s = 0.f;
        #pragma unroll
        for (int j = 0; j < 4; ++j) { e[j] = __expf(v[j] - mx); s += e[j]; }
        #pragma unroll
        for (int off = 32; off > 0; off >>= 1) s += __shfl_down(s, off);
        if (lane == 0) ssum[wid] = s;
        __syncthreads();
        float inv = 1.f / (ssum[0] + ssum[1] + ssum[2] + ssum[3]);
        float4 o;
        o.x = e[0] * inv; o.y = e[1] * inv; o.z = e[2] * inv; o.w = e[3] * inv;
        *(float4*)(ksm + ((size_t)b * 16 + kc) * NPIX + tid * 4) = o;
    }
}

// ---------------- K3: pack q/v (bf16 tiled) + content lambda (fused) --------
__global__ __launch_bounds__(256, 2) void k_packlc(const float* __restrict__ qkv,
    const float* __restrict__ sA, const float* __restrict__ sB,
    const float* __restrict__ ksm,
    ushort16_t* __restrict__ qt_g, ushort16_t* __restrict__ vt_g,
    ushort16_t* __restrict__ lc_g)
{
    int bx = blockIdx.x, t = threadIdx.x;
    if (bx < 128) {
        // q part: qt_g[n][kh][bh][8]; one (n, bh) per thread
        int bh = t & 31, nn = (t >> 5) & 7;
        int n = bx * 8 + nn;
        int b = bh >> 2, h = bh & 3;
        float vals[16];
        #pragma unroll
        for (int k = 0; k < 16; ++k) {
            int ch = h * 16 + k;
            vals[k] = qkv[((size_t)b * TOTCH + ch) * NPIX + n] * sA[ch] + sB[ch];
        }
        uint4 w0, w1;
        w0.x = pk2(vals[0], vals[1]);  w0.y = pk2(vals[2], vals[3]);
        w0.z = pk2(vals[4], vals[5]);  w0.w = pk2(vals[6], vals[7]);
        w1.x = pk2(vals[8], vals[9]);  w1.y = pk2(vals[10], vals[11]);
        w1.z = pk2(vals[12], vals[13]); w1.w = pk2(vals[14], vals[15]);
        *(uint4*)&qt_g[(size_t)n * 512 + bh * 8]       = w0;
        *(uint4*)&qt_g[(size_t)n * 512 + 256 + bh * 8] = w1;
    } else if (bx < 512) {
        // v part: vt_g[b][mt][vh][vt][mq][vl][8]
        int gi = (bx - 128) * 256 + t;   // < 98304
        int m8 = gi & 127;
        int vg = (gi >> 7) % 96;
        int b  = gi / (96 * 128);
        int m  = m8 * 8;
        int row = 80 + vg;
        float a = sA[row], bb = sB[row];
        const float* p = qkv + ((size_t)b * TOTCH + row) * NPIX + m;
        float4 f0 = *(const float4*)p;
        float4 f1 = *(const float4*)(p + 4);
        uint4 w;
        w.x = pk2(f0.x * a + bb, f0.y * a + bb);
        w.y = pk2(f0.z * a + bb, f0.w * a + bb);
        w.z = pk2(f1.x * a + bb, f1.y * a + bb);
        w.w = pk2(f1.z * a + bb, f1.w * a + bb);
        int mt = m >> 5, mq = (m >> 3) & 3;
        int vhh = vg / 48, vtt = (vg % 48) >> 4, vl = vg & 15;
        size_t idx = ((((size_t)b * 32 + mt) * 2 + vhh) * 3 + vtt) * 512
                   + mq * 128 + vl * 8;
        *(uint4*)&vt_g[idx] = w;
    } else {
        // content lambda: thread t owns m in [4t, 4t+4) -> coalesced rows
        int gi = bx - 512;
        int v = gi % 96, b = gi / 96;
        int row = 80 + v;
        float a = sA[row], bb = sB[row];
        const float* vp = qkv + ((size_t)b * TOTCH + row) * NPIX;
        const float* kp = ksm + (size_t)b * 16 * NPIX;
        float4 vv = *(const float4*)(vp + t * 4);
        float4 vhat;
        vhat.x = vv.x * a + bb; vhat.y = vv.y * a + bb;
        vhat.z = vv.z * a + bb; vhat.w = vv.w * a + bb;
        float acc[16];
        #pragma unroll
        for (int k = 0; k < 16; ++k) {
            float4 kk = *(const float4*)(kp + (size_t)k * NPIX + t * 4);
            acc[k] = kk.x * vhat.x + kk.y * vhat.y
                   + kk.z * vhat.z + kk.w * vhat.w;
        }
        #pragma unroll
        for (int k = 0; k < 16; ++k) {
            #pragma unroll
            for (int off = 32; off > 0; off >>= 1)
                acc[k] += __shfl_down(acc[k], off);
        }
        __shared__ float red[16][4];
        int wid = t >> 6, lane = t & 63;
        if (lane == 0) {
            #pragma unroll
            for (int k = 0; k < 16; ++k) red[k][wid] = acc[k];
        }
        __syncthreads();
        int vhh = v / 48, vtt = (v % 48) >> 4, vl = v & 15;
        size_t plane = ((size_t)(b * 2 + vhh) * 3 + vtt) * 512;
        if (t < 16) {
            int k = t;
            float val = red[k][0] + red[k][1] + red[k][2] + red[k][3];
            lc_g[plane + (k >> 3) * 128 + vl * 8 + (k & 7)] = f2bf(val);
        } else if (t < 18) {
            int mq = 2 + (t - 16);
            uint4 z; z.x = z.y = z.z = z.w = 0u;
            *(uint4*)&lc_g[plane + mq * 128 + vl * 8] = z;
        }
    }
}

// ---------------- K4: fused MFMA lambda, asm-pinned pipeline (r13) ----------
// r13 = r12 + amdgpu_waves_per_eu(2,2): target occupancy 2 waves/EU (= what
// the 256-block x 8-wave grid achieves anyway) so the allocator gets a
// 256-VGPR budget and the vbuf/pos pipeline lives in registers instead of
// spilling to scratch (r10/r12 WRITE_SIZE showed +12 MB spill traffic).
__global__ __attribute__((amdgpu_flat_work_group_size(512, 512)))
__attribute__((amdgpu_waves_per_eu(2, 2)))
void k_main(const float* __restrict__ pos,
    const ushort16_t* __restrict__ qt_g, const ushort16_t* __restrict__ vt_g,
    const ushort16_t* __restrict__ lc_g, float* __restrict__ out)
{
    __shared__ __align__(16) ushort16_t S_s[2][8256];   // 2 x 16.1 KB
    int tid  = threadIdx.x;
    int lane = tid & 63;
    int wave = tid >> 6;
    int n0 = blockIdx.x * 4;

    int col1 = lane & 31, half = lane >> 5;
    int nsub = wave & 3, mc0 = wave >> 2;

    // phase-1 write addressing
    int colw  = (col1 & 3) * 4 + nsub;            // lds col = h*4 + n
    int key3w = nsub + ((col1 & 1) << 2);         // n + 4*(h&1)
    int basew = (col1 >> 2) * 1032 + colw * 64 + half * 4;

    // phase-2 read addressing (wave = b; lane col = (h,n), k-quad)
    int b2 = wave;
    int c2 = lane & 15, kq = lane >> 4;
    int h2 = c2 >> 2, n2 = c2 & 3;
    int key3r = n2 + ((h2 & 1) << 2);
    int baser = b2 * 1032 + (h2 * 4 + n2) * 64;

    short8 qfr = *(const short8*)(qt_g + (size_t)(n0 + nsub) * 512
                                  + half * 256 + col1 * 8);

    floatx4 acc[6];
    #pragma unroll
    for (int vg = 0; vg < 6; ++vg) acc[vg] = floatx4{0.f, 0.f, 0.f, 0.f};

    floatx16 z16;
    #pragma unroll
    for (int i = 0; i < 16; ++i) z16[i] = 0.f;

    const float* pA = pos + ((size_t)(n0 + nsub) * 1024 + mc0 * 32 + col1) * 16
                    + half * 8;
    const ushort16_t* pV = vt_g + (size_t)b2 * 98304 + lane * 8;

    // pos double-slot: slot j holds pos for iteration with (i&1)==j.
    float4 pa[2], pb[2];
    gload4f(pa[0], pA);
    gload4f(pb[0], pA + 4);
    gload4f(pa[1], pA + 1024);
    gload4f(pb[1], pA + 1028);

    short8 vbuf[12];

    #pragma unroll
    for (int i = 0; i < 16; ++i) {
        // issue this iteration's 12 v-fragments (mt = 2i, 2i+1)
        const ushort16_t* pVi = pV + (size_t)i * 6144;
        #pragma unroll
        for (int vg = 0; vg < 6; ++vg)
            gload8h(vbuf[vg], pVi + vg * 512);
        #pragma unroll
        for (int vg = 0; vg < 6; ++vg)
            gload8h(vbuf[6 + vg], pVi + 3072 + vg * 512);

        if (i == 0) {   // ensure iter-0 pos arrived (leaves pos1 + v0 in flight)
            asm volatile("s_waitcnt vmcnt(14)");
            __builtin_amdgcn_sched_barrier(0);
        }

        // ---- phase 1: P[m32, (b,h)32] for (nsub, mc0) ----
        {
            float4 a0c = pa[i & 1], a1c = pb[i & 1];
            uint4 aw;
            aw.x = pk2(a0c.x, a0c.y); aw.y = pk2(a0c.z, a0c.w);
            aw.z = pk2(a1c.x, a1c.y); aw.w = pk2(a1c.z, a1c.w);
            short8 afr = *(short8*)&aw;
            floatx16 d = __builtin_amdgcn_mfma_f32_32x32x16_bf16(
                afr, qfr, z16, 0, 0, 0);
            ushort16_t* Sb = S_s[i & 1];
            #pragma unroll
            for (int q = 0; q < 4; ++q) {
                int slot = (mc0 * 4 + q) ^ key3w;
                uint2 wv;
                wv.x = pk2(d[q * 4 + 0], d[q * 4 + 1]);
                wv.y = pk2(d[q * 4 + 2], d[q * 4 + 3]);
                *(uint2*)&Sb[basew + slot * 8] = wv;
            }
        }

        // refill the just-consumed pos slot for iteration i+2
        if (i < 14) {
            const float* p = pA + (size_t)(i + 2) * 1024;
            gload4f(pa[i & 1], p);
            gload4f(pb[i & 1], p + 4);
        }

        __builtin_amdgcn_s_waitcnt(LGKM0_ONLY);
        __builtin_amdgcn_s_barrier();

        // counted wait: v-loads of this iter done; pos loads stay in flight
        if (i < 14) asm volatile("s_waitcnt vmcnt(2)");
        else        asm volatile("s_waitcnt vmcnt(0)");
        __builtin_amdgcn_sched_barrier(0);

        // ---- phase 2 ----
        {
            const ushort16_t* Sr = S_s[i & 1];
            short8 bs0 = *(const short8*)&Sr[baser + (kq ^ key3r) * 8];
            #pragma unroll
            for (int vg = 0; vg < 6; ++vg)
                acc[vg] = __builtin_amdgcn_mfma_f32_16x16x32_bf16(
                    vbuf[vg], bs0, acc[vg], 0, 0, 0);
            short8 bs1 = *(const short8*)&Sr[baser + ((4 + kq) ^ key3r) * 8];
            #pragma unroll
            for (int vg = 0; vg < 6; ++vg)
                acc[vg] = __builtin_amdgcn_mfma_f32_16x16x32_bf16(
                    vbuf[6 + vg], bs1, acc[vg], 0, 0, 0);
        }
    }

    // ---- content-lambda extension (pure-register, no LDS) ----
    {
        short8 bsq = {0, 0, 0, 0, 0, 0, 0, 0};
        if (kq < 2)
            bsq = *(const short8*)(qt_g + (size_t)(n0 + n2) * 512
                                   + kq * 256 + (b2 * 4 + h2) * 8);
        const ushort16_t* lsrc = lc_g + (size_t)b2 * 3072 + lane * 8;
        #pragma unroll
        for (int vg = 0; vg < 6; ++vg) {
            short8 lv = *(const short8*)(lsrc + vg * 512);
            acc[vg] = __builtin_amdgcn_mfma_f32_16x16x32_bf16(
                lv, bsq, acc[vg], 0, 0, 0);
        }
    }

    // ---- epilogue: plain stores, each out element written exactly once ----
    {
        #pragma unroll
        for (int vg = 0; vg < 6; ++vg) {
            int vbase = (vg / 3) * 48 + (vg % 3) * 16 + kq * 4;
            #pragma unroll
            for (int r = 0; r < 4; ++r) {
                int v = vbase + r;
                out[(size_t)(b2 * 384 + h2 * 96 + v) * 1024 + n0 + n2]
                    = acc[vg][r];
            }
        }
    }
}

extern "C" void kernel_launch(void* const* d_in, const int* in_sizes, int n_in,
                              void* d_out, int out_size, void* d_ws, size_t ws_size,
                              hipStream_t stream) {
    const float* x   = (const float*)d_in[0];
    const float* Wq  = (const float*)d_in[1];
    const float* Wk  = (const float*)d_in[2];
    const float* Wv  = (const float*)d_in[3];
    const float* gq  = (const float*)d_in[4];
    const float* bq  = (const float*)d_in[5];
    const float* gv  = (const float*)d_in[6];
    const float* bv  = (const float*)d_in[7];
    const float* pos = (const float*)d_in[8];
    float* out = (float*)d_out;
    float* ws  = (float*)d_ws;

    float* qkv = ws;
    float* sA  = ws + 1441792;
    float* sB  = ws + 1441968;
    float* ksm = ws + 1442144;
    ushort16_t* qt_g = (ushort16_t*)(ws + 1573216);
    ushort16_t* vt_g = (ushort16_t*)(ws + 1835360);
    ushort16_t* lc_g = (ushort16_t*)(ws + 2228576);
    ushort16_t* wbf  = (ushort16_t*)(ws + 3813728);

    k_wt<<<dim3(4), dim3(256), 0, stream>>>(Wq, Wk, Wv, wbf);
    k_proj<<<dim3(256), dim3(256), 0, stream>>>(x, wbf, qkv);
    k_bnsm<<<dim3(288), dim3(256), 0, stream>>>(qkv, gq, bq, gv, bv, sA, sB, ksm);
    k_packlc<<<dim3(1280), dim3(256), 0, stream>>>(qkv, sA, sB, ksm,
                                                   qt_g, vt_g, lc_g);
    k_main<<<dim3(256), dim3(512), 0, stream>>>(pos, qt_g, vt_g, lc_g, out);
}